// Round 1
// baseline (608.992 us; speedup 1.0000x reference)
//
#include <hip/hip_runtime.h>
#include <math.h>

// Problem constants (match reference)
#define B_  4
#define NQ_ 8192
#define D_  256
#define H_  8
#define L_  4
#define K_  4
#define DH_ 32
#define NV_ 5440
#define TQ_ 16   // query tile for projection kernel
#define TS_ 8    // query tile for sampling kernel

// ---------------------------------------------------------------------------
// Kernel 1: v = value @ W_v + b_v, stored permuted as [B][H][NV][DH]
// one block = (b, 4 value rows), 256 threads = output cols
// ---------------------------------------------------------------------------
__global__ __launch_bounds__(256) void k_vproj(const float* __restrict__ value,
                                               const float* __restrict__ Wv,
                                               const float* __restrict__ bv,
                                               float* __restrict__ vperm) {
    __shared__ __align__(16) float vsh[4][256];
    const int blk = blockIdx.x;
    const int b   = blk / (NV_ / 4);
    const int r0  = (blk % (NV_ / 4)) * 4;
    const int t   = threadIdx.x;

    #pragma unroll
    for (int r = 0; r < 4; ++r)
        vsh[r][t] = value[((size_t)(b * NV_ + r0 + r)) * D_ + t];
    __syncthreads();

    float bias = bv[t];
    float a0 = bias, a1 = bias, a2 = bias, a3 = bias;
    for (int c = 0; c < D_; c += 4) {
        float w0 = Wv[(c + 0) * D_ + t];
        float w1 = Wv[(c + 1) * D_ + t];
        float w2 = Wv[(c + 2) * D_ + t];
        float w3 = Wv[(c + 3) * D_ + t];
        #pragma unroll
        for (int r = 0; r < 4; ++r) {
            const float4 v4 = *(const float4*)&vsh[r][c];
            float s = v4.x * w0 + v4.y * w1 + v4.z * w2 + v4.w * w3;
            if (r == 0) a0 += s; else if (r == 1) a1 += s; else if (r == 2) a2 += s; else a3 += s;
        }
    }
    const int h = t >> 5, dh = t & 31;
    size_t base = ((size_t)(b * H_ + h) * NV_ + r0) * DH_ + dh;
    vperm[base]           = a0;
    vperm[base + DH_]     = a1;
    vperm[base + 2 * DH_] = a2;
    vperm[base + 3 * DH_] = a3;
}

// ---------------------------------------------------------------------------
// Kernel 2: query projections + tanh + softmax epilogue -> params
// params per (b,q): [H][L][8] = {attn0..3, xA, xB, yA, yB}   (256 floats)
// block = (b, 16 queries), 256 threads
// ---------------------------------------------------------------------------
__global__ __launch_bounds__(256) void k_proj(const float* __restrict__ query,
                                              const float* __restrict__ refpts,
                                              const float* __restrict__ Wt, const float* __restrict__ bt,
                                              const float* __restrict__ Wf, const float* __restrict__ bf,
                                              const float* __restrict__ Wlv, const float* __restrict__ blv,
                                              const float* __restrict__ Wp, const float* __restrict__ bp,
                                              float* __restrict__ params) {
    __shared__ __align__(16) float qsh[TQ_][260];   // padded, rows 16B aligned
    __shared__ float lg[288][TQ_ + 1];              // logits [col][ql]
    const int b  = blockIdx.y;
    const int q0 = blockIdx.x * TQ_;
    const int t  = threadIdx.x;

    // stage query tile (coalesced)
    for (int i = t; i < TQ_ * 256; i += 256) {
        int ql = i >> 8, c = i & 255;
        qsh[ql][c] = query[((size_t)(b * NQ_ + q0 + ql)) * D_ + c];
    }
    __syncthreads();

    // GEMM: 288 cols, each thread owns col t (+ col 256+t for t<32)
    for (int col = t; col < 288; col += 256) {
        const float* Wsel; int str, wc; float bias;
        if (col < 64)       { Wsel = Wt;  str = 64;  wc = col;       bias = bt[wc]; }
        else if (col < 128) { Wsel = Wf;  str = 64;  wc = col - 64;  bias = bf[wc]; }
        else if (col < 160) { Wsel = Wlv; str = 32;  wc = col - 128; bias = blv[wc]; }
        else                { Wsel = Wp;  str = 128; wc = col - 160; bias = bp[wc]; }
        float acc[TQ_];
        #pragma unroll
        for (int i = 0; i < TQ_; ++i) acc[i] = 0.f;
        for (int c = 0; c < 256; c += 4) {
            float w0 = Wsel[(c + 0) * str + wc];
            float w1 = Wsel[(c + 1) * str + wc];
            float w2 = Wsel[(c + 2) * str + wc];
            float w3 = Wsel[(c + 3) * str + wc];
            #pragma unroll
            for (int ql = 0; ql < TQ_; ++ql) {
                const float4 qv = *(const float4*)&qsh[ql][c];
                acc[ql] += qv.x * w0 + qv.y * w1 + qv.z * w2 + qv.w * w3;
            }
        }
        #pragma unroll
        for (int ql = 0; ql < TQ_; ++ql) lg[col][ql] = acc[ql] + bias;
    }
    __syncthreads();

    // epilogue: one item per (ql, h, l)
    for (int item = t; item < TQ_ * 32; item += 256) {
        const int ql = item >> 5;
        const int hl = item & 31;
        const int h  = hl >> 2, l = hl & 3;

        const float tA = tanhf(lg[hl * 2 + 0][ql]);
        const float tB = tanhf(lg[hl * 2 + 1][ql]);
        const float fA = tanhf(lg[64 + hl * 2 + 0][ql]);
        const float fB = tanhf(lg[64 + hl * 2 + 1][ql]);

        // level softmax (over l' for this h)
        const float l0 = lg[128 + h * 4 + 0][ql];
        const float l1 = lg[128 + h * 4 + 1][ql];
        const float l2 = lg[128 + h * 4 + 2][ql];
        const float l3 = lg[128 + h * 4 + 3][ql];
        const float lm = fmaxf(fmaxf(l0, l1), fmaxf(l2, l3));
        const float e0 = __expf(l0 - lm), e1 = __expf(l1 - lm);
        const float e2 = __expf(l2 - lm), e3 = __expf(l3 - lm);
        const float lsum = e0 + e1 + e2 + e3;
        const float lwv = ((l == 0) ? e0 : (l == 1) ? e1 : (l == 2) ? e2 : e3) / lsum;

        // point softmax (over k for this (h,l))
        const float p0 = lg[160 + hl * 4 + 0][ql];
        const float p1 = lg[160 + hl * 4 + 1][ql];
        const float p2 = lg[160 + hl * 4 + 2][ql];
        const float p3 = lg[160 + hl * 4 + 3][ql];
        const float pmx = fmaxf(fmaxf(p0, p1), fmaxf(p2, p3));
        const float q0e = __expf(p0 - pmx), q1e = __expf(p1 - pmx);
        const float q2e = __expf(p2 - pmx), q3e = __expf(p3 - pmx);
        const float inv = lwv / (q0e + q1e + q2e + q3e);

        // coords (grid_sample align_corners=False): x = loc*W - 0.5
        const int q = q0 + ql;
        const float rx = refpts[(((size_t)(b * NQ_ + q)) * L_ + l) * 2 + 0];
        const float ry = refpts[(((size_t)(b * NQ_ + q)) * L_ + l) * 2 + 1];
        const float Wlf = (float)(64 >> l);
        const float Hlf = (float)(64 >> l);
        const float xA = fminf(fmaxf(rx + tA / Wlf, 0.f), 1.f) * Wlf - 0.5f;
        const float xB = fminf(fmaxf(rx + tB / Wlf, 0.f), 1.f) * Wlf - 0.5f;
        const float yA = fminf(fmaxf(ry + fA / Hlf, 0.f), 1.f) * Hlf - 0.5f;
        const float yB = fminf(fmaxf(ry + fB / Hlf, 0.f), 1.f) * Hlf - 0.5f;

        float* pp = params + ((size_t)(b * NQ_ + q)) * 256 + hl * 8;
        pp[0] = q0e * inv; pp[1] = q1e * inv; pp[2] = q2e * inv; pp[3] = q3e * inv;
        pp[4] = xA; pp[5] = xB; pp[6] = yA; pp[7] = yB;
    }
}

// ---------------------------------------------------------------------------
// Kernel 3: bilinear sampling + attention accumulation -> mid [B][NQ][H][DH]
// block = (b, 8 queries), thread = (h, dh)
// ---------------------------------------------------------------------------
__global__ __launch_bounds__(256) void k_sample(const float* __restrict__ vperm,
                                                const float* __restrict__ params,
                                                float* __restrict__ mid) {
    __shared__ float pm[TS_][256];
    const int b  = blockIdx.y;
    const int q0 = blockIdx.x * TS_;
    const int t  = threadIdx.x;
    const int h  = t >> 5, dh = t & 31;

    for (int i = t; i < TS_ * 256; i += 256)
        pm[i >> 8][i & 255] = params[((size_t)(b * NQ_ + q0)) * 256 + i];
    __syncthreads();

    const float* vb_h = vperm + ((size_t)(b * H_ + h)) * NV_ * DH_ + dh;
    const int lsi_tab[4] = {0, 4096, 5120, 5376};

    for (int ql = 0; ql < TS_; ++ql) {
        float acc = 0.f;
        #pragma unroll
        for (int l = 0; l < L_; ++l) {
            const int Wl = 64 >> l;
            const int Hl = 64 >> l;
            const float* vb = vb_h + (size_t)lsi_tab[l] * DH_;
            const float* p  = &pm[ql][(h * L_ + l) * 8];
            const float a0 = p[0], a1 = p[1], a2 = p[2], a3 = p[3];
            const float xA = p[4], xB = p[5], yA = p[6], yB = p[7];
            #pragma unroll
            for (int k = 0; k < 4; ++k) {
                const float x  = (k & 2) ? xB : xA;   // kt = k>>1
                const float y  = (k & 1) ? yB : yA;   // kf = k&1
                const float ak = (k == 0) ? a0 : (k == 1) ? a1 : (k == 2) ? a2 : a3;
                const float x0f = floorf(x), y0f = floorf(y);
                const float fx = x - x0f, fy = y - y0f;
                const int x0 = (int)x0f, y0 = (int)y0f;
                const bool xin0 = (x0 >= 0) && (x0 < Wl);
                const bool xin1 = (x0 + 1 >= 0) && (x0 + 1 < Wl);
                const bool yin0 = (y0 >= 0) && (y0 < Hl);
                const bool yin1 = (y0 + 1 >= 0) && (y0 + 1 < Hl);
                float v00 = 0.f, v10 = 0.f, v01 = 0.f, v11 = 0.f;
                if (yin0) {
                    const float* row = vb + (size_t)(y0 * Wl) * DH_;
                    if (xin0) v00 = row[x0 * DH_];
                    if (xin1) v10 = row[(x0 + 1) * DH_];
                }
                if (yin1) {
                    const float* row = vb + (size_t)((y0 + 1) * Wl) * DH_;
                    if (xin0) v01 = row[x0 * DH_];
                    if (xin1) v11 = row[(x0 + 1) * DH_];
                }
                const float s = (1.f - fx) * (1.f - fy) * v00 + fx * (1.f - fy) * v10
                              + (1.f - fx) * fy * v01 + fx * fy * v11;
                acc += ak * s;
            }
        }
        mid[((size_t)(b * NQ_ + q0 + ql)) * 256 + t] = acc;
    }
}

// ---------------------------------------------------------------------------
// Kernel 4: out = mid @ W_o + b_o   (in-place safe: block-local rows only)
// block = 8 rows, 256 threads = cols
// ---------------------------------------------------------------------------
__global__ __launch_bounds__(256) void k_out(const float* __restrict__ mid,
                                             const float* __restrict__ Wo,
                                             const float* __restrict__ bo,
                                             float* __restrict__ out) {
    __shared__ __align__(16) float msh[8][256];
    const size_t r0 = (size_t)blockIdx.x * 8;
    const int t = threadIdx.x;

    for (int i = t; i < 8 * 256; i += 256)
        msh[i >> 8][i & 255] = mid[r0 * 256 + i];
    __syncthreads();

    float acc[8];
    const float bias = bo[t];
    #pragma unroll
    for (int r = 0; r < 8; ++r) acc[r] = bias;
    for (int c = 0; c < 256; c += 4) {
        float w0 = Wo[(c + 0) * 256 + t];
        float w1 = Wo[(c + 1) * 256 + t];
        float w2 = Wo[(c + 2) * 256 + t];
        float w3 = Wo[(c + 3) * 256 + t];
        #pragma unroll
        for (int r = 0; r < 8; ++r) {
            const float4 m4 = *(const float4*)&msh[r][c];
            acc[r] += m4.x * w0 + m4.y * w1 + m4.z * w2 + m4.w * w3;
        }
    }
    #pragma unroll
    for (int r = 0; r < 8; ++r) out[(r0 + r) * 256 + t] = acc[r];
}

// ---------------------------------------------------------------------------
extern "C" void kernel_launch(void* const* d_in, const int* in_sizes, int n_in,
                              void* d_out, int out_size, void* d_ws, size_t ws_size,
                              hipStream_t stream) {
    const float* query = (const float*)d_in[0];
    const float* refp  = (const float*)d_in[1];
    const float* value = (const float*)d_in[2];
    // d_in[3] spatial_shapes, d_in[4] level_start_index: compile-time constants
    const float* Wt = (const float*)d_in[5];
    const float* bt = (const float*)d_in[6];
    const float* Wf = (const float*)d_in[7];
    const float* bf = (const float*)d_in[8];
    const float* Wl = (const float*)d_in[9];
    const float* bl = (const float*)d_in[10];
    const float* Wp = (const float*)d_in[11];
    const float* bp = (const float*)d_in[12];
    const float* Wv = (const float*)d_in[13];
    const float* bv = (const float*)d_in[14];
    const float* Wo = (const float*)d_in[15];
    const float* bo = (const float*)d_in[16];

    float* vperm  = (float*)d_ws;                          // B*H*NV*DH  = 5,570,560 f
    float* params = vperm + (size_t)B_ * H_ * NV_ * DH_;   // B*NQ*256   = 8,388,608 f
    float* mid    = (float*)d_out;                         // reuse d_out as scratch

    k_vproj<<<B_ * NV_ / 4, 256, 0, stream>>>(value, Wv, bv, vperm);
    k_proj<<<dim3(NQ_ / TQ_, B_), 256, 0, stream>>>(query, refp, Wt, bt, Wf, bf,
                                                    Wl, bl, Wp, bp, params);
    k_sample<<<dim3(NQ_ / TS_, B_), 256, 0, stream>>>(vperm, params, mid);
    k_out<<<B_ * NQ_ / 8, 256, 0, stream>>>(mid, Wo, bo, (float*)d_out);
}

// Round 3
// 332.630 us; speedup vs baseline: 1.8308x; 1.8308x over previous
//
#include <hip/hip_runtime.h>
#include <math.h>

// Problem constants (match reference)
#define B_  4
#define NQ_ 8192
#define D_  256
#define H_  8
#define L_  4
#define K_  4
#define DH_ 32
#define NV_ 5440
#define TS_ 8    // query tile for sampling kernel

typedef short bf16x8 __attribute__((ext_vector_type(8)));
typedef float f32x4  __attribute__((ext_vector_type(4)));

__device__ __forceinline__ ushort f2bf(float f) {
    union { float f; unsigned u; } v; v.f = f;
    return (ushort)((v.u + 0x7FFF + ((v.u >> 16) & 1)) >> 16);
}

// ---------------------------------------------------------------------------
// Weight transpose+convert: out_bf16[n][256] = in_f32[k][N=256] transposed
// ---------------------------------------------------------------------------
__global__ __launch_bounds__(256) void k_cvtw(const float* __restrict__ in,
                                              ushort* __restrict__ out) {
    const int n = blockIdx.x, k = threadIdx.x;
    out[n * 256 + k] = f2bf(in[k * 256 + n]);
}

// Concatenated query-weight transpose+convert: out[n][256], n in [0,288)
__global__ __launch_bounds__(256) void k_cvtwq(const float* __restrict__ Wt,
                                               const float* __restrict__ Wf,
                                               const float* __restrict__ Wlv,
                                               const float* __restrict__ Wp,
                                               ushort* __restrict__ out) {
    const int n = blockIdx.x, k = threadIdx.x;
    float v;
    if (n < 64)       v = Wt[k * 64 + n];
    else if (n < 128) v = Wf[k * 64 + (n - 64)];
    else if (n < 160) v = Wlv[k * 32 + (n - 128)];
    else              v = Wp[k * 128 + (n - 160)];
    out[n * 256 + k] = f2bf(v);
}

// ---------------------------------------------------------------------------
// MFMA GEMM: C[M][N] = A[M][256](f32) @ Bt[N][256](bf16)^T (+bias)
// tile 128 x NT, 4 waves in 2x2, 16x16x32 bf16 MFMA, BK=32
// MODE 0: out proj  -> C[row*256+col] = acc + bias[col]
// MODE 1: vproj     -> vperm[((b*8+h)*NV + s)*32 + dh] = acc + bias[col]
// MODE 2: qproj     -> logits[row*288+col] = acc   (bias added in epilogue)
// ---------------------------------------------------------------------------
template<int NT, int MODE>
__global__ __launch_bounds__(256) void k_gemm(const float* __restrict__ A,
                                              const ushort* __restrict__ Bt,
                                              const float* __restrict__ bias,
                                              float* __restrict__ C) {
    constexpr int NFN = NT / 32;              // n-frags per wave (128->4, 96->3)
    __shared__ ushort As[128 * 32];
    __shared__ ushort Bs[NT * 32];
    const int m0   = blockIdx.x * 128;
    const int n0   = blockIdx.y * NT;
    const int t    = threadIdx.x;
    const int w    = t >> 6;
    const int lane = t & 63;
    const int wm   = (w >> 1) * 64;
    const int wn   = (w & 1) * (NT / 2);
    const int lm   = lane & 15;               // frag row/col within 16
    const int quad = lane >> 4;               // k-chunk selector

    f32x4 acc[4][NFN];
    #pragma unroll
    for (int i = 0; i < 4; ++i)
        #pragma unroll
        for (int j = 0; j < NFN; ++j)
            acc[i][j] = (f32x4)(0.f);

    for (int kc = 0; kc < 256; kc += 32) {
        __syncthreads();
        // stage A tile: 128 rows x 32 k, fp32 -> bf16 (4-float chunks, 8/row)
        #pragma unroll
        for (int i = 0; i < 4; ++i) {
            const int c   = t + i * 256;
            const int row = c >> 3, ko = (c & 7) * 4;
            const float4 v = *(const float4*)&A[(size_t)(m0 + row) * 256 + kc + ko];
            ushort4 u; u.x = f2bf(v.x); u.y = f2bf(v.y); u.z = f2bf(v.z); u.w = f2bf(v.w);
            *(ushort4*)&As[row * 32 + ko] = u;
        }
        // stage B tile: NT rows x 32 k (bf16), 4-ushort chunks, 8 chunks/row
        #pragma unroll
        for (int i = 0; i < NT / 32; ++i) {
            const int c   = t + i * 256;
            const int row = c >> 3, ko = (c & 7) * 4;
            *(ushort4*)&Bs[row * 32 + ko] =
                *(const ushort4*)&Bt[(size_t)(n0 + row) * 256 + kc + ko];
        }
        __syncthreads();

        bf16x8 af[4], bfr[NFN];
        #pragma unroll
        for (int mf = 0; mf < 4; ++mf)
            af[mf] = *(const bf16x8*)&As[(wm + mf * 16 + lm) * 32 + quad * 8];
        #pragma unroll
        for (int nf = 0; nf < NFN; ++nf)
            bfr[nf] = *(const bf16x8*)&Bs[(wn + nf * 16 + lm) * 32 + quad * 8];
        #pragma unroll
        for (int mf = 0; mf < 4; ++mf)
            #pragma unroll
            for (int nf = 0; nf < NFN; ++nf)
                acc[mf][nf] = __builtin_amdgcn_mfma_f32_16x16x32_bf16(
                    af[mf], bfr[nf], acc[mf][nf], 0, 0, 0);
    }

    // epilogue store: C/D layout col=lane&15, row=quad*4+reg
    #pragma unroll
    for (int mf = 0; mf < 4; ++mf) {
        #pragma unroll
        for (int nf = 0; nf < NFN; ++nf) {
            const f32x4 a = acc[mf][nf];
            const int col   = n0 + wn + nf * 16 + lm;
            const int rbase = m0 + wm + mf * 16 + quad * 4;
            #pragma unroll
            for (int r = 0; r < 4; ++r) {
                const int row = rbase + r;
                const float v = a[r];
                if (MODE == 0) {
                    C[(size_t)row * 256 + col] = v + bias[col];
                } else if (MODE == 1) {
                    const int b = row / NV_, s = row - b * NV_;
                    const int h = col >> 5, dh = col & 31;
                    C[(((size_t)(b * H_ + h)) * NV_ + s) * DH_ + dh] = v + bias[col];
                } else {
                    C[(size_t)row * 288 + col] = v;
                }
            }
        }
    }
}

// ---------------------------------------------------------------------------
// Epilogue: logits[32768][288] (+bias) -> tanh/softmax/coords -> params
// params per (b,q): [H][L][8] = {attn0..3, xA, xB, yA, yB}
// ---------------------------------------------------------------------------
__global__ __launch_bounds__(256) void k_epi(const float* __restrict__ logits,
                                             const float* __restrict__ refpts,
                                             const float* __restrict__ bt,
                                             const float* __restrict__ bfq,
                                             const float* __restrict__ blv,
                                             const float* __restrict__ bp,
                                             float* __restrict__ params) {
    const int item = blockIdx.x * 256 + threadIdx.x;   // 32768*32 items
    const int qg = item >> 5;                          // global row b*NQ+q
    const int hl = item & 31;
    const int h = hl >> 2, l = hl & 3;
    const float* lgr = logits + (size_t)qg * 288;

    const float tA = tanhf(lgr[hl * 2 + 0] + bt[hl * 2 + 0]);
    const float tB = tanhf(lgr[hl * 2 + 1] + bt[hl * 2 + 1]);
    const float fA = tanhf(lgr[64 + hl * 2 + 0] + bfq[hl * 2 + 0]);
    const float fB = tanhf(lgr[64 + hl * 2 + 1] + bfq[hl * 2 + 1]);

    const float l0 = lgr[128 + h * 4 + 0] + blv[h * 4 + 0];
    const float l1 = lgr[128 + h * 4 + 1] + blv[h * 4 + 1];
    const float l2 = lgr[128 + h * 4 + 2] + blv[h * 4 + 2];
    const float l3 = lgr[128 + h * 4 + 3] + blv[h * 4 + 3];
    const float lm = fmaxf(fmaxf(l0, l1), fmaxf(l2, l3));
    const float e0 = __expf(l0 - lm), e1 = __expf(l1 - lm);
    const float e2 = __expf(l2 - lm), e3 = __expf(l3 - lm);
    const float lsum = e0 + e1 + e2 + e3;
    const float lwv = ((l == 0) ? e0 : (l == 1) ? e1 : (l == 2) ? e2 : e3) / lsum;

    const float p0 = lgr[160 + hl * 4 + 0] + bp[hl * 4 + 0];
    const float p1 = lgr[160 + hl * 4 + 1] + bp[hl * 4 + 1];
    const float p2 = lgr[160 + hl * 4 + 2] + bp[hl * 4 + 2];
    const float p3 = lgr[160 + hl * 4 + 3] + bp[hl * 4 + 3];
    const float pmx = fmaxf(fmaxf(p0, p1), fmaxf(p2, p3));
    const float q0e = __expf(p0 - pmx), q1e = __expf(p1 - pmx);
    const float q2e = __expf(p2 - pmx), q3e = __expf(p3 - pmx);
    const float inv = lwv / (q0e + q1e + q2e + q3e);

    const float rx = refpts[((size_t)qg * L_ + l) * 2 + 0];
    const float ry = refpts[((size_t)qg * L_ + l) * 2 + 1];
    const float Wlf = (float)(64 >> l);
    const float Hlf = (float)(64 >> l);
    const float xA = fminf(fmaxf(rx + tA / Wlf, 0.f), 1.f) * Wlf - 0.5f;
    const float xB = fminf(fmaxf(rx + tB / Wlf, 0.f), 1.f) * Wlf - 0.5f;
    const float yA = fminf(fmaxf(ry + fA / Hlf, 0.f), 1.f) * Hlf - 0.5f;
    const float yB = fminf(fmaxf(ry + fB / Hlf, 0.f), 1.f) * Hlf - 0.5f;

    float* pp = params + (size_t)qg * 256 + hl * 8;
    pp[0] = q0e * inv; pp[1] = q1e * inv; pp[2] = q2e * inv; pp[3] = q3e * inv;
    pp[4] = xA; pp[5] = xB; pp[6] = yA; pp[7] = yB;
}

// ---------------------------------------------------------------------------
// Bilinear sampling + attention accumulation -> mid [B*NQ][256]
// block = (b, 8 queries), thread = (h, dh)
// ---------------------------------------------------------------------------
__global__ __launch_bounds__(256) void k_sample(const float* __restrict__ vperm,
                                                const float* __restrict__ params,
                                                float* __restrict__ mid) {
    __shared__ float pm[TS_][256];
    const int b  = blockIdx.y;
    const int q0 = blockIdx.x * TS_;
    const int t  = threadIdx.x;
    const int h  = t >> 5, dh = t & 31;

    for (int i = t; i < TS_ * 256; i += 256)
        pm[i >> 8][i & 255] = params[((size_t)(b * NQ_ + q0)) * 256 + i];
    __syncthreads();

    const float* vb_h = vperm + ((size_t)(b * H_ + h)) * NV_ * DH_ + dh;
    const int lsi_tab[4] = {0, 4096, 5120, 5376};

    for (int ql = 0; ql < TS_; ++ql) {
        float acc = 0.f;
        #pragma unroll
        for (int l = 0; l < L_; ++l) {
            const int Wl = 64 >> l;
            const int Hl = 64 >> l;
            const float* vb = vb_h + (size_t)lsi_tab[l] * DH_;
            const float* p  = &pm[ql][(h * L_ + l) * 8];
            const float a0 = p[0], a1 = p[1], a2 = p[2], a3 = p[3];
            const float xA = p[4], xB = p[5], yA = p[6], yB = p[7];
            #pragma unroll
            for (int k = 0; k < 4; ++k) {
                const float x  = (k & 2) ? xB : xA;
                const float y  = (k & 1) ? yB : yA;
                const float ak = (k == 0) ? a0 : (k == 1) ? a1 : (k == 2) ? a2 : a3;
                const float x0f = floorf(x), y0f = floorf(y);
                const float fx = x - x0f, fy = y - y0f;
                const int x0 = (int)x0f, y0 = (int)y0f;
                const bool xin0 = (x0 >= 0) && (x0 < Wl);
                const bool xin1 = (x0 + 1 >= 0) && (x0 + 1 < Wl);
                const bool yin0 = (y0 >= 0) && (y0 < Hl);
                const bool yin1 = (y0 + 1 >= 0) && (y0 + 1 < Hl);
                float v00 = 0.f, v10 = 0.f, v01 = 0.f, v11 = 0.f;
                if (yin0) {
                    const float* row = vb + (size_t)(y0 * Wl) * DH_;
                    if (xin0) v00 = row[x0 * DH_];
                    if (xin1) v10 = row[(x0 + 1) * DH_];
                }
                if (yin1) {
                    const float* row = vb + (size_t)((y0 + 1) * Wl) * DH_;
                    if (xin0) v01 = row[x0 * DH_];
                    if (xin1) v11 = row[(x0 + 1) * DH_];
                }
                const float s = (1.f - fx) * (1.f - fy) * v00 + fx * (1.f - fy) * v10
                              + (1.f - fx) * fy * v01 + fx * fy * v11;
                acc += ak * s;
            }
        }
        mid[((size_t)(b * NQ_ + q0 + ql)) * 256 + t] = acc;
    }
}

// ---------------------------------------------------------------------------
extern "C" void kernel_launch(void* const* d_in, const int* in_sizes, int n_in,
                              void* d_out, int out_size, void* d_ws, size_t ws_size,
                              hipStream_t stream) {
    const float* query = (const float*)d_in[0];
    const float* refp  = (const float*)d_in[1];
    const float* value = (const float*)d_in[2];
    const float* Wt = (const float*)d_in[5];
    const float* bt = (const float*)d_in[6];
    const float* Wf = (const float*)d_in[7];
    const float* bf = (const float*)d_in[8];
    const float* Wl = (const float*)d_in[9];
    const float* bl = (const float*)d_in[10];
    const float* Wp = (const float*)d_in[11];
    const float* bp = (const float*)d_in[12];
    const float* Wv = (const float*)d_in[13];
    const float* bv = (const float*)d_in[14];
    const float* Wo = (const float*)d_in[15];
    const float* bo = (const float*)d_in[16];

    char* wsb = (char*)d_ws;
    float*  vperm  = (float*)wsb;                          // 22,282,240 B
    float*  params = (float*)(wsb + 22282240);             // 33,554,432 B
    float*  logits = (float*)(wsb + 55836672);             // 37,748,736 B
    float*  mid    = logits;                               // aliases logits (dead after k_epi)
    ushort* Wvt    = (ushort*)(wsb + 93585408);            // 131,072 B
    ushort* Wot    = (ushort*)(wsb + 93716480);            // 131,072 B
    ushort* Wqt    = (ushort*)(wsb + 93847552);            // 147,456 B

    // weight converts (tiny)
    k_cvtw<<<256, 256, 0, stream>>>(Wv, Wvt);
    k_cvtw<<<256, 256, 0, stream>>>(Wo, Wot);
    k_cvtwq<<<288, 256, 0, stream>>>(Wt, Wf, Wl, Wp, Wqt);

    // value projection (MFMA), permuted store
    k_gemm<128, 1><<<dim3(170, 2), 256, 0, stream>>>(value, Wvt, bv, vperm);
    // query projections (MFMA) -> raw logits
    k_gemm<96, 2><<<dim3(256, 3), 256, 0, stream>>>(query, Wqt, nullptr, logits);
    // epilogue -> params
    k_epi<<<4096, 256, 0, stream>>>(logits, refp, bt, bf, bl, bp, params);
    // bilinear sampling + attention
    k_sample<<<dim3(NQ_ / TS_, B_), 256, 0, stream>>>(vperm, params, mid);
    // output projection (MFMA)
    k_gemm<128, 0><<<dim3(256, 2), 256, 0, stream>>>(mid, Wot, bo, (float*)d_out);
}

// Round 4
// 275.338 us; speedup vs baseline: 2.2118x; 1.2081x over previous
//
#include <hip/hip_runtime.h>
#include <math.h>

// Problem constants (match reference)
#define B_  4
#define NQ_ 8192
#define D_  256
#define H_  8
#define L_  4
#define K_  4
#define DH_ 32
#define NV_ 5440

// Padded value-slab geometry (per (b,h)): levels with 1-px zero border
// L0: 66x66=4356, L1: 34x34=1156, L2: 18x18=324, L3: 10x10=100 -> 5936 rows
#define SLAB_ 5936

typedef short bf16x8 __attribute__((ext_vector_type(8)));
typedef float f32x4  __attribute__((ext_vector_type(4)));

__device__ __forceinline__ ushort f2bf(float f) {
    union { float f; unsigned u; } v; v.f = f;
    return (ushort)((v.u + 0x7FFF + ((v.u >> 16) & 1)) >> 16);
}

// ---------------------------------------------------------------------------
// Zero the padded vperm buffer (borders must be 0; interior overwritten later)
// grid: SLAB_*32/1024 = 5936 blocks, 256 threads, float4 each
// ---------------------------------------------------------------------------
__global__ __launch_bounds__(256) void k_zero(float* __restrict__ p) {
    const size_t i = ((size_t)blockIdx.x * 256 + threadIdx.x) * 4;
    *(f32x4*)(p + i) = (f32x4)(0.f);
}

// ---------------------------------------------------------------------------
// Weight transpose+convert: out_bf16[n][256] = in_f32[k][N=256] transposed
// ---------------------------------------------------------------------------
__global__ __launch_bounds__(256) void k_cvtw(const float* __restrict__ in,
                                              ushort* __restrict__ out) {
    const int n = blockIdx.x, k = threadIdx.x;
    out[n * 256 + k] = f2bf(in[k * 256 + n]);
}

// Concatenated query-weight transpose+convert: out[n][256], n in [0,288)
__global__ __launch_bounds__(256) void k_cvtwq(const float* __restrict__ Wt,
                                               const float* __restrict__ Wf,
                                               const float* __restrict__ Wlv,
                                               const float* __restrict__ Wp,
                                               ushort* __restrict__ out) {
    const int n = blockIdx.x, k = threadIdx.x;
    float v;
    if (n < 64)       v = Wt[k * 64 + n];
    else if (n < 128) v = Wf[k * 64 + (n - 64)];
    else if (n < 160) v = Wlv[k * 32 + (n - 128)];
    else              v = Wp[k * 128 + (n - 160)];
    out[n * 256 + k] = f2bf(v);
}

// ---------------------------------------------------------------------------
// MFMA GEMM: C[M][N] = A[M][256](f32) @ Bt[N][256](bf16)^T (+bias)
// tile 128 x NT, 4 waves in 2x2, 16x16x32 bf16 MFMA, BK=32
// MODE 0: out proj  -> C[row*256+col] = acc + bias[col]
// MODE 1: vproj     -> padded slab write (zero-border layout)
// MODE 2: qproj     -> logits[row*288+col] = acc   (bias added in epilogue)
// ---------------------------------------------------------------------------
template<int NT, int MODE>
__global__ __launch_bounds__(256) void k_gemm(const float* __restrict__ A,
                                              const ushort* __restrict__ Bt,
                                              const float* __restrict__ bias,
                                              float* __restrict__ C) {
    constexpr int NFN = NT / 32;              // n-frags per wave (128->4, 96->3)
    __shared__ ushort As[128 * 32];
    __shared__ ushort Bs[NT * 32];
    const int m0   = blockIdx.x * 128;
    const int n0   = blockIdx.y * NT;
    const int t    = threadIdx.x;
    const int w    = t >> 6;
    const int lane = t & 63;
    const int wm   = (w >> 1) * 64;
    const int wn   = (w & 1) * (NT / 2);
    const int lm   = lane & 15;               // frag row/col within 16
    const int quad = lane >> 4;               // k-chunk selector

    f32x4 acc[4][NFN];
    #pragma unroll
    for (int i = 0; i < 4; ++i)
        #pragma unroll
        for (int j = 0; j < NFN; ++j)
            acc[i][j] = (f32x4)(0.f);

    for (int kc = 0; kc < 256; kc += 32) {
        __syncthreads();
        // stage A tile: 128 rows x 32 k, fp32 -> bf16 (4-float chunks, 8/row)
        #pragma unroll
        for (int i = 0; i < 4; ++i) {
            const int c   = t + i * 256;
            const int row = c >> 3, ko = (c & 7) * 4;
            const float4 v = *(const float4*)&A[(size_t)(m0 + row) * 256 + kc + ko];
            ushort4 u; u.x = f2bf(v.x); u.y = f2bf(v.y); u.z = f2bf(v.z); u.w = f2bf(v.w);
            *(ushort4*)&As[row * 32 + ko] = u;
        }
        // stage B tile: NT rows x 32 k (bf16), 4-ushort chunks, 8 chunks/row
        #pragma unroll
        for (int i = 0; i < NT / 32; ++i) {
            const int c   = t + i * 256;
            const int row = c >> 3, ko = (c & 7) * 4;
            *(ushort4*)&Bs[row * 32 + ko] =
                *(const ushort4*)&Bt[(size_t)(n0 + row) * 256 + kc + ko];
        }
        __syncthreads();

        bf16x8 af[4], bfr[NFN];
        #pragma unroll
        for (int mf = 0; mf < 4; ++mf)
            af[mf] = *(const bf16x8*)&As[(wm + mf * 16 + lm) * 32 + quad * 8];
        #pragma unroll
        for (int nf = 0; nf < NFN; ++nf)
            bfr[nf] = *(const bf16x8*)&Bs[(wn + nf * 16 + lm) * 32 + quad * 8];
        #pragma unroll
        for (int mf = 0; mf < 4; ++mf)
            #pragma unroll
            for (int nf = 0; nf < NFN; ++nf)
                acc[mf][nf] = __builtin_amdgcn_mfma_f32_16x16x32_bf16(
                    af[mf], bfr[nf], acc[mf][nf], 0, 0, 0);
    }

    // epilogue store: C/D layout col=lane&15, row=quad*4+reg
    #pragma unroll
    for (int mf = 0; mf < 4; ++mf) {
        #pragma unroll
        for (int nf = 0; nf < NFN; ++nf) {
            const f32x4 a = acc[mf][nf];
            const int col   = n0 + wn + nf * 16 + lm;
            const int rbase = m0 + wm + mf * 16 + quad * 4;
            #pragma unroll
            for (int r = 0; r < 4; ++r) {
                const int row = rbase + r;
                const float v = a[r];
                if (MODE == 0) {
                    C[(size_t)row * 256 + col] = v + bias[col];
                } else if (MODE == 1) {
                    // padded slab write
                    const int b = row / NV_, s = row - b * NV_;
                    const int h = col >> 5, dh = col & 31;
                    const int l = (s >= 5376) ? 3 : (s >= 5120) ? 2 : (s >= 4096) ? 1 : 0;
                    const int lsi_[4] = {0, 4096, 5120, 5376};
                    const int po_[4]  = {0, 4356, 5512, 5836};
                    const int o  = s - lsi_[l];
                    const int Wl = 64 >> l;
                    const int y  = o >> (6 - l);
                    const int x  = o & (Wl - 1);
                    const int prow = po_[l] + (y + 1) * (Wl + 2) + (x + 1);
                    C[(((size_t)(b * H_ + h)) * SLAB_ + prow) * 32 + dh] = v + bias[col];
                } else {
                    C[(size_t)row * 288 + col] = v;
                }
            }
        }
    }
}

// ---------------------------------------------------------------------------
// Epilogue: logits[32768][288] (+bias) -> tanh/softmax/coords -> params
// params per (b,q): [H][L][8] = {attn0..3, xA, xB, yA, yB}
// ---------------------------------------------------------------------------
__global__ __launch_bounds__(256) void k_epi(const float* __restrict__ logits,
                                             const float* __restrict__ refpts,
                                             const float* __restrict__ bt,
                                             const float* __restrict__ bfq,
                                             const float* __restrict__ blv,
                                             const float* __restrict__ bp,
                                             float* __restrict__ params) {
    const int item = blockIdx.x * 256 + threadIdx.x;   // 32768*32 items
    const int qg = item >> 5;                          // global row b*NQ+q
    const int hl = item & 31;
    const int h = hl >> 2, l = hl & 3;
    const float* lgr = logits + (size_t)qg * 288;

    const float tA = tanhf(lgr[hl * 2 + 0] + bt[hl * 2 + 0]);
    const float tB = tanhf(lgr[hl * 2 + 1] + bt[hl * 2 + 1]);
    const float fA = tanhf(lgr[64 + hl * 2 + 0] + bfq[hl * 2 + 0]);
    const float fB = tanhf(lgr[64 + hl * 2 + 1] + bfq[hl * 2 + 1]);

    const float l0 = lgr[128 + h * 4 + 0] + blv[h * 4 + 0];
    const float l1 = lgr[128 + h * 4 + 1] + blv[h * 4 + 1];
    const float l2 = lgr[128 + h * 4 + 2] + blv[h * 4 + 2];
    const float l3 = lgr[128 + h * 4 + 3] + blv[h * 4 + 3];
    const float lm = fmaxf(fmaxf(l0, l1), fmaxf(l2, l3));
    const float e0 = __expf(l0 - lm), e1 = __expf(l1 - lm);
    const float e2 = __expf(l2 - lm), e3 = __expf(l3 - lm);
    const float lsum = e0 + e1 + e2 + e3;
    const float lwv = ((l == 0) ? e0 : (l == 1) ? e1 : (l == 2) ? e2 : e3) / lsum;

    const float p0 = lgr[160 + hl * 4 + 0] + bp[hl * 4 + 0];
    const float p1 = lgr[160 + hl * 4 + 1] + bp[hl * 4 + 1];
    const float p2 = lgr[160 + hl * 4 + 2] + bp[hl * 4 + 2];
    const float p3 = lgr[160 + hl * 4 + 3] + bp[hl * 4 + 3];
    const float pmx = fmaxf(fmaxf(p0, p1), fmaxf(p2, p3));
    const float q0e = __expf(p0 - pmx), q1e = __expf(p1 - pmx);
    const float q2e = __expf(p2 - pmx), q3e = __expf(p3 - pmx);
    const float inv = lwv / (q0e + q1e + q2e + q3e);

    const float rx = refpts[((size_t)qg * L_ + l) * 2 + 0];
    const float ry = refpts[((size_t)qg * L_ + l) * 2 + 1];
    const float Wlf = (float)(64 >> l);
    const float Hlf = (float)(64 >> l);
    const float xA = fminf(fmaxf(rx + tA / Wlf, 0.f), 1.f) * Wlf - 0.5f;
    const float xB = fminf(fmaxf(rx + tB / Wlf, 0.f), 1.f) * Wlf - 0.5f;
    const float yA = fminf(fmaxf(ry + fA / Hlf, 0.f), 1.f) * Hlf - 0.5f;
    const float yB = fminf(fmaxf(ry + fB / Hlf, 0.f), 1.f) * Hlf - 0.5f;

    float* pp = params + (size_t)qg * 256 + hl * 8;
    pp[0] = q0e * inv; pp[1] = q1e * inv; pp[2] = q2e * inv; pp[3] = q3e * inv;
    pp[4] = xA; pp[5] = xB; pp[6] = yA; pp[7] = yB;
}

// ---------------------------------------------------------------------------
// Bilinear sampling + attention accumulation -> mid [B*NQ][256]
// Padded slabs: no bounds checks. Thread = (qs, h, dh4); float4 over dh.
// block = 256 thr covers 8 queries (4 concurrent x 2 iterations)
// ---------------------------------------------------------------------------
__global__ __launch_bounds__(256) void k_sample(const float* __restrict__ vperm,
                                                const float* __restrict__ params,
                                                float* __restrict__ mid) {
    __shared__ float pm[8][264];   // per q: [h][33] padded (bank-spread h reads)
    const int b   = blockIdx.y;
    const int q0  = blockIdx.x * 8;
    const int t   = threadIdx.x;
    const int qs  = t >> 6;
    const int sub = t & 63;
    const int h   = sub >> 3;
    const int dh4 = sub & 7;

    for (int i = t; i < 8 * 256; i += 256) {
        const int q = i >> 8, c = i & 255;
        pm[q][(c >> 5) * 33 + (c & 31)] = params[((size_t)(b * NQ_ + q0 + q)) * 256 + c];
    }
    __syncthreads();

    const float* vb = vperm + ((size_t)(b * H_ + h)) * SLAB_ * 32 + dh4 * 4;
    const int po_[4] = {0, 4356, 5512, 5836};

    #pragma unroll
    for (int i = 0; i < 2; ++i) {
        const int ql = qs + i * 4;
        f32x4 acc = (f32x4)(0.f);
        #pragma unroll
        for (int l = 0; l < L_; ++l) {
            const int W2 = (64 >> l) + 2;
            const float* vl = vb + (size_t)po_[l] * 32;
            const float* p  = &pm[ql][h * 33 + l * 8];
            const float a0 = p[0], a1 = p[1], a2 = p[2], a3 = p[3];
            const float xA = p[4], xB = p[5], yA = p[6], yB = p[7];
            const float xa0 = floorf(xA), xb0 = floorf(xB);
            const float ya0 = floorf(yA), yb0 = floorf(yB);
            const float fxa = xA - xa0, fxb = xB - xb0;
            const float fya = yA - ya0, fyb = yB - yb0;
            const int pxa = (int)xa0 + 1, pxb = (int)xb0 + 1;
            const int pya = (int)ya0 + 1, pyb = (int)yb0 + 1;
            #pragma unroll
            for (int k = 0; k < 4; ++k) {
                const int   px = (k & 2) ? pxb : pxa;
                const int   py = (k & 1) ? pyb : pya;
                const float fx = (k & 2) ? fxb : fxa;
                const float fy = (k & 1) ? fyb : fya;
                const float ak = (k == 0) ? a0 : (k == 1) ? a1 : (k == 2) ? a2 : a3;
                const float* c = vl + (size_t)(py * W2 + px) * 32;
                const f32x4 v00 = *(const f32x4*)c;
                const f32x4 v10 = *(const f32x4*)(c + 32);
                const f32x4 v01 = *(const f32x4*)(c + W2 * 32);
                const f32x4 v11 = *(const f32x4*)(c + (W2 + 1) * 32);
                const float gx = 1.f - fx, gy = 1.f - fy;
                acc += v00 * (ak * gx * gy) + v10 * (ak * fx * gy)
                     + v01 * (ak * gx * fy) + v11 * (ak * fx * fy);
            }
        }
        *(f32x4*)&mid[((size_t)(b * NQ_ + q0 + ql)) * 256 + sub * 4] = acc;
    }
}

// ---------------------------------------------------------------------------
// Kernel 4 epilogue GEMM handled by k_gemm<128,0>
// ---------------------------------------------------------------------------
extern "C" void kernel_launch(void* const* d_in, const int* in_sizes, int n_in,
                              void* d_out, int out_size, void* d_ws, size_t ws_size,
                              hipStream_t stream) {
    const float* query = (const float*)d_in[0];
    const float* refp  = (const float*)d_in[1];
    const float* value = (const float*)d_in[2];
    const float* Wt = (const float*)d_in[5];
    const float* bt = (const float*)d_in[6];
    const float* Wf = (const float*)d_in[7];
    const float* bf = (const float*)d_in[8];
    const float* Wl = (const float*)d_in[9];
    const float* bl = (const float*)d_in[10];
    const float* Wp = (const float*)d_in[11];
    const float* bp = (const float*)d_in[12];
    const float* Wv = (const float*)d_in[13];
    const float* bv = (const float*)d_in[14];
    const float* Wo = (const float*)d_in[15];
    const float* bo = (const float*)d_in[16];

    char* wsb = (char*)d_ws;
    float*  vperm  = (float*)wsb;                          // 24,313,856 B (padded slabs)
    float*  params = (float*)(wsb + 24313856);             // 33,554,432 B
    float*  logits = (float*)(wsb + 57868288);             // 37,748,736 B
    float*  mid    = logits;                               // aliases logits (dead after k_epi)
    ushort* Wvt    = (ushort*)(wsb + 95617024);            // 131,072 B
    ushort* Wot    = (ushort*)(wsb + 95748096);            // 131,072 B
    ushort* Wqt    = (ushort*)(wsb + 95879168);            // 147,456 B

    // weight converts (tiny) + padded slab zeroing
    k_cvtw<<<256, 256, 0, stream>>>(Wv, Wvt);
    k_cvtw<<<256, 256, 0, stream>>>(Wo, Wot);
    k_cvtwq<<<288, 256, 0, stream>>>(Wt, Wf, Wl, Wp, Wqt);
    k_zero<<<SLAB_ * 32 / 1024, 256, 0, stream>>>(vperm);

    // value projection (MFMA), padded permuted store
    k_gemm<128, 1><<<dim3(170, 2), 256, 0, stream>>>(value, Wvt, bv, vperm);
    // query projections (MFMA) -> raw logits
    k_gemm<96, 2><<<dim3(256, 3), 256, 0, stream>>>(query, Wqt, nullptr, logits);
    // epilogue -> params
    k_epi<<<4096, 256, 0, stream>>>(logits, refp, bt, bf, bl, bp, params);
    // bilinear sampling + attention (padded, float4, no bounds checks)
    k_sample<<<dim3(NQ_ / 8, B_), 256, 0, stream>>>(vperm, params, mid);
    // output projection (MFMA)
    k_gemm<128, 0><<<dim3(256, 2), 256, 0, stream>>>(mid, Wot, bo, (float*)d_out);
}

// Round 5
// 260.440 us; speedup vs baseline: 2.3383x; 1.0572x over previous
//
#include <hip/hip_runtime.h>
#include <math.h>

// Problem constants (match reference)
#define B_  4
#define NQ_ 8192
#define D_  256
#define H_  8
#define L_  4
#define K_  4
#define DH_ 32
#define NV_ 5440

// Padded value-slab geometry (per (b,h)): levels with 1-px zero border
// L0: 66x66=4356, L1: 34x34=1156, L2: 18x18=324, L3: 10x10=100 -> 5936 rows
#define SLAB_ 5936

typedef short bf16x8 __attribute__((ext_vector_type(8)));
typedef float f32x4  __attribute__((ext_vector_type(4)));
typedef unsigned short u16x8 __attribute__((ext_vector_type(8)));

__device__ __forceinline__ ushort f2bf(float f) {
    union { float f; unsigned u; } v; v.f = f;
    return (ushort)((v.u + 0x7FFF + ((v.u >> 16) & 1)) >> 16);
}
__device__ __forceinline__ float bf2f(ushort u) {
    union { unsigned u; float f; } v; v.u = ((unsigned)u) << 16;
    return v.f;
}

// ---------------------------------------------------------------------------
// Zero the padded vperm buffer (bf16): grid*256*16 bytes total
// ---------------------------------------------------------------------------
__global__ __launch_bounds__(256) void k_zero(uint4* __restrict__ p) {
    p[(size_t)blockIdx.x * 256 + threadIdx.x] = make_uint4(0, 0, 0, 0);
}

// ---------------------------------------------------------------------------
// Row-major f32 -> bf16 convert (8 elements/thread)
// ---------------------------------------------------------------------------
__global__ __launch_bounds__(256) void k_cvta(const float* __restrict__ in,
                                              ushort* __restrict__ out) {
    const size_t base = ((size_t)blockIdx.x * 256 + threadIdx.x) * 8;
    const float4 a = *(const float4*)(in + base);
    const float4 b = *(const float4*)(in + base + 4);
    u16x8 u;
    u[0] = f2bf(a.x); u[1] = f2bf(a.y); u[2] = f2bf(a.z); u[3] = f2bf(a.w);
    u[4] = f2bf(b.x); u[5] = f2bf(b.y); u[6] = f2bf(b.z); u[7] = f2bf(b.w);
    *(u16x8*)(out + base) = u;
}

// ---------------------------------------------------------------------------
// Weight transpose+convert: out_bf16[n][256] = in_f32[k][N=256] transposed
// ---------------------------------------------------------------------------
__global__ __launch_bounds__(256) void k_cvtw(const float* __restrict__ in,
                                              ushort* __restrict__ out) {
    const int n = blockIdx.x, k = threadIdx.x;
    out[n * 256 + k] = f2bf(in[k * 256 + n]);
}

// Concatenated query-weight transpose+convert: out[n][256], n in [0,288)
__global__ __launch_bounds__(256) void k_cvtwq(const float* __restrict__ Wt,
                                               const float* __restrict__ Wf,
                                               const float* __restrict__ Wlv,
                                               const float* __restrict__ Wp,
                                               ushort* __restrict__ out) {
    const int n = blockIdx.x, k = threadIdx.x;
    float v;
    if (n < 64)       v = Wt[k * 64 + n];
    else if (n < 128) v = Wf[k * 64 + (n - 64)];
    else if (n < 160) v = Wlv[k * 32 + (n - 128)];
    else              v = Wp[k * 128 + (n - 160)];
    out[n * 256 + k] = f2bf(v);
}

// ---------------------------------------------------------------------------
// MFMA GEMM: C[M][N] = A[M][256] @ Bt[N][256]^T (+bias)
// tile 128 x NT, 4 waves in 2x2, 16x16x32 bf16 MFMA, BK=32
// AF32: 1 = A is fp32 (convert on stage), 0 = A already bf16
// MODE 0: out proj  -> f32 C[row*256+col] = acc + bias[col]
// MODE 1: vproj     -> bf16 padded slab write (zero-border layout)
// MODE 2: qproj     -> f32 logits[row*288+col] = acc (bias in epilogue)
// ---------------------------------------------------------------------------
template<int NT, int MODE, int AF32>
__global__ __launch_bounds__(256) void k_gemm(const void* __restrict__ Ap,
                                              const ushort* __restrict__ Bt,
                                              const float* __restrict__ bias,
                                              void* __restrict__ Cp) {
    constexpr int NFN = NT / 32;              // n-frags per wave (128->4, 96->3)
    __shared__ ushort As[128 * 32];
    __shared__ ushort Bs[NT * 32];
    const int m0   = blockIdx.x * 128;
    const int n0   = blockIdx.y * NT;
    const int t    = threadIdx.x;
    const int w    = t >> 6;
    const int lane = t & 63;
    const int wm   = (w >> 1) * 64;
    const int wn   = (w & 1) * (NT / 2);
    const int lm   = lane & 15;               // frag row/col within 16
    const int quad = lane >> 4;               // k-chunk selector

    f32x4 acc[4][NFN];
    #pragma unroll
    for (int i = 0; i < 4; ++i)
        #pragma unroll
        for (int j = 0; j < NFN; ++j)
            acc[i][j] = (f32x4)(0.f);

    for (int kc = 0; kc < 256; kc += 32) {
        __syncthreads();
        // stage A tile: 128 rows x 32 k
        if (AF32) {
            const float* A = (const float*)Ap;
            #pragma unroll
            for (int i = 0; i < 4; ++i) {
                const int c   = t + i * 256;
                const int row = c >> 3, ko = (c & 7) * 4;
                const float4 v = *(const float4*)&A[(size_t)(m0 + row) * 256 + kc + ko];
                ushort4 u; u.x = f2bf(v.x); u.y = f2bf(v.y); u.z = f2bf(v.z); u.w = f2bf(v.w);
                *(ushort4*)&As[row * 32 + ko] = u;
            }
        } else {
            const ushort* A = (const ushort*)Ap;
            #pragma unroll
            for (int i = 0; i < 2; ++i) {
                const int c   = t + i * 256;       // 16B chunks: 4 per row
                const int row = c >> 2, ko = (c & 3) * 8;
                *(u16x8*)&As[row * 32 + ko] =
                    *(const u16x8*)&A[(size_t)(m0 + row) * 256 + kc + ko];
            }
        }
        // stage B tile: NT rows x 32 k (bf16), 16B chunks (guarded for NT=96)
        #pragma unroll
        for (int i = 0; i < 2; ++i) {
            const int c = t + i * 256;
            if (NT == 128 || c < NT * 4) {
                const int row = c >> 2, ko = (c & 3) * 8;
                *(u16x8*)&Bs[row * 32 + ko] =
                    *(const u16x8*)&Bt[(size_t)(n0 + row) * 256 + kc + ko];
            }
        }
        __syncthreads();

        bf16x8 af[4], bfr[NFN];
        #pragma unroll
        for (int mf = 0; mf < 4; ++mf)
            af[mf] = *(const bf16x8*)&As[(wm + mf * 16 + lm) * 32 + quad * 8];
        #pragma unroll
        for (int nf = 0; nf < NFN; ++nf)
            bfr[nf] = *(const bf16x8*)&Bs[(wn + nf * 16 + lm) * 32 + quad * 8];
        #pragma unroll
        for (int mf = 0; mf < 4; ++mf)
            #pragma unroll
            for (int nf = 0; nf < NFN; ++nf)
                acc[mf][nf] = __builtin_amdgcn_mfma_f32_16x16x32_bf16(
                    af[mf], bfr[nf], acc[mf][nf], 0, 0, 0);
    }

    // epilogue store: C/D layout col=lane&15, row=quad*4+reg
    #pragma unroll
    for (int mf = 0; mf < 4; ++mf) {
        #pragma unroll
        for (int nf = 0; nf < NFN; ++nf) {
            const f32x4 a = acc[mf][nf];
            const int col   = n0 + wn + nf * 16 + lm;
            const int rbase = m0 + wm + mf * 16 + quad * 4;
            #pragma unroll
            for (int r = 0; r < 4; ++r) {
                const int row = rbase + r;
                const float v = a[r];
                if (MODE == 0) {
                    ((float*)Cp)[(size_t)row * 256 + col] = v + bias[col];
                } else if (MODE == 1) {
                    // padded bf16 slab write
                    const int b = row / NV_, s = row - b * NV_;
                    const int h = col >> 5, dh = col & 31;
                    const int l = (s >= 5376) ? 3 : (s >= 5120) ? 2 : (s >= 4096) ? 1 : 0;
                    const int lsi_[4] = {0, 4096, 5120, 5376};
                    const int po_[4]  = {0, 4356, 5512, 5836};
                    const int o  = s - lsi_[l];
                    const int Wl = 64 >> l;
                    const int y  = o >> (6 - l);
                    const int x  = o & (Wl - 1);
                    const int prow = po_[l] + (y + 1) * (Wl + 2) + (x + 1);
                    ((ushort*)Cp)[(((size_t)(b * H_ + h)) * SLAB_ + prow) * 32 + dh] =
                        f2bf(v + bias[col]);
                } else {
                    ((float*)Cp)[(size_t)row * 288 + col] = v;
                }
            }
        }
    }
}

// ---------------------------------------------------------------------------
// Epilogue: logits[32768][288] (+bias) -> tanh/softmax/coords -> params
// params per (b,q): [H][L][8] = {attn0..3, xA, xB, yA, yB}
// ---------------------------------------------------------------------------
__global__ __launch_bounds__(256) void k_epi(const float* __restrict__ logits,
                                             const float* __restrict__ refpts,
                                             const float* __restrict__ bt,
                                             const float* __restrict__ bfq,
                                             const float* __restrict__ blv,
                                             const float* __restrict__ bp,
                                             float* __restrict__ params) {
    const int item = blockIdx.x * 256 + threadIdx.x;   // 32768*32 items
    const int qg = item >> 5;                          // global row b*NQ+q
    const int hl = item & 31;
    const int h = hl >> 2, l = hl & 3;
    const float* lgr = logits + (size_t)qg * 288;

    const float tA = tanhf(lgr[hl * 2 + 0] + bt[hl * 2 + 0]);
    const float tB = tanhf(lgr[hl * 2 + 1] + bt[hl * 2 + 1]);
    const float fA = tanhf(lgr[64 + hl * 2 + 0] + bfq[hl * 2 + 0]);
    const float fB = tanhf(lgr[64 + hl * 2 + 1] + bfq[hl * 2 + 1]);

    const float l0 = lgr[128 + h * 4 + 0] + blv[h * 4 + 0];
    const float l1 = lgr[128 + h * 4 + 1] + blv[h * 4 + 1];
    const float l2 = lgr[128 + h * 4 + 2] + blv[h * 4 + 2];
    const float l3 = lgr[128 + h * 4 + 3] + blv[h * 4 + 3];
    const float lm = fmaxf(fmaxf(l0, l1), fmaxf(l2, l3));
    const float e0 = __expf(l0 - lm), e1 = __expf(l1 - lm);
    const float e2 = __expf(l2 - lm), e3 = __expf(l3 - lm);
    const float lsum = e0 + e1 + e2 + e3;
    const float lwv = ((l == 0) ? e0 : (l == 1) ? e1 : (l == 2) ? e2 : e3) / lsum;

    const float p0 = lgr[160 + hl * 4 + 0] + bp[hl * 4 + 0];
    const float p1 = lgr[160 + hl * 4 + 1] + bp[hl * 4 + 1];
    const float p2 = lgr[160 + hl * 4 + 2] + bp[hl * 4 + 2];
    const float p3 = lgr[160 + hl * 4 + 3] + bp[hl * 4 + 3];
    const float pmx = fmaxf(fmaxf(p0, p1), fmaxf(p2, p3));
    const float q0e = __expf(p0 - pmx), q1e = __expf(p1 - pmx);
    const float q2e = __expf(p2 - pmx), q3e = __expf(p3 - pmx);
    const float inv = lwv / (q0e + q1e + q2e + q3e);

    const float rx = refpts[((size_t)qg * L_ + l) * 2 + 0];
    const float ry = refpts[((size_t)qg * L_ + l) * 2 + 1];
    const float Wlf = (float)(64 >> l);
    const float Hlf = (float)(64 >> l);
    const float xA = fminf(fmaxf(rx + tA / Wlf, 0.f), 1.f) * Wlf - 0.5f;
    const float xB = fminf(fmaxf(rx + tB / Wlf, 0.f), 1.f) * Wlf - 0.5f;
    const float yA = fminf(fmaxf(ry + fA / Hlf, 0.f), 1.f) * Hlf - 0.5f;
    const float yB = fminf(fmaxf(ry + fB / Hlf, 0.f), 1.f) * Hlf - 0.5f;

    float* pp = params + (size_t)qg * 256 + hl * 8;
    pp[0] = q0e * inv; pp[1] = q1e * inv; pp[2] = q2e * inv; pp[3] = q3e * inv;
    pp[4] = xA; pp[5] = xB; pp[6] = yA; pp[7] = yB;
}

// ---------------------------------------------------------------------------
// Bilinear sampling + attention accumulation -> mid bf16 [B*NQ][256]
// Padded bf16 slabs: no bounds checks. Thread = (qs, h, dh4).
// ---------------------------------------------------------------------------
__global__ __launch_bounds__(256) void k_sample(const ushort* __restrict__ vperm,
                                                const float* __restrict__ params,
                                                ushort* __restrict__ mid) {
    __shared__ float pm[8][264];   // per q: [h][33] padded (bank-spread h reads)
    const int b   = blockIdx.y;
    const int q0  = blockIdx.x * 8;
    const int t   = threadIdx.x;
    const int qs  = t >> 6;
    const int sub = t & 63;
    const int h   = sub >> 3;
    const int dh4 = sub & 7;

    for (int i = t; i < 8 * 256; i += 256) {
        const int q = i >> 8, c = i & 255;
        pm[q][(c >> 5) * 33 + (c & 31)] = params[((size_t)(b * NQ_ + q0 + q)) * 256 + c];
    }
    __syncthreads();

    const ushort* vb = vperm + ((size_t)(b * H_ + h)) * SLAB_ * 32 + dh4 * 4;
    const int po_[4] = {0, 4356, 5512, 5836};

    #pragma unroll
    for (int i = 0; i < 2; ++i) {
        const int ql = qs + i * 4;
        f32x4 acc = (f32x4)(0.f);
        #pragma unroll
        for (int l = 0; l < L_; ++l) {
            const int W2 = (64 >> l) + 2;
            const ushort* vl = vb + (size_t)po_[l] * 32;
            const float* p  = &pm[ql][h * 33 + l * 8];
            const float a0 = p[0], a1 = p[1], a2 = p[2], a3 = p[3];
            const float xA = p[4], xB = p[5], yA = p[6], yB = p[7];
            const float xa0 = floorf(xA), xb0 = floorf(xB);
            const float ya0 = floorf(yA), yb0 = floorf(yB);
            const float fxa = xA - xa0, fxb = xB - xb0;
            const float fya = yA - ya0, fyb = yB - yb0;
            const int pxa = (int)xa0 + 1, pxb = (int)xb0 + 1;
            const int pya = (int)ya0 + 1, pyb = (int)yb0 + 1;
            #pragma unroll
            for (int k = 0; k < 4; ++k) {
                const int   px = (k & 2) ? pxb : pxa;
                const int   py = (k & 1) ? pyb : pya;
                const float fx = (k & 2) ? fxb : fxa;
                const float fy = (k & 1) ? fyb : fya;
                const float ak = (k == 0) ? a0 : (k == 1) ? a1 : (k == 2) ? a2 : a3;
                const ushort* c = vl + (size_t)(py * W2 + px) * 32;
                const ushort4 u00 = *(const ushort4*)c;
                const ushort4 u10 = *(const ushort4*)(c + 32);
                const ushort4 u01 = *(const ushort4*)(c + W2 * 32);
                const ushort4 u11 = *(const ushort4*)(c + (W2 + 1) * 32);
                const float gx = 1.f - fx, gy = 1.f - fy;
                const float w00 = ak * gx * gy, w10 = ak * fx * gy;
                const float w01 = ak * gx * fy, w11 = ak * fx * fy;
                f32x4 v;
                v.x = bf2f(u00.x) * w00 + bf2f(u10.x) * w10 + bf2f(u01.x) * w01 + bf2f(u11.x) * w11;
                v.y = bf2f(u00.y) * w00 + bf2f(u10.y) * w10 + bf2f(u01.y) * w01 + bf2f(u11.y) * w11;
                v.z = bf2f(u00.z) * w00 + bf2f(u10.z) * w10 + bf2f(u01.z) * w01 + bf2f(u11.z) * w11;
                v.w = bf2f(u00.w) * w00 + bf2f(u10.w) * w10 + bf2f(u01.w) * w01 + bf2f(u11.w) * w11;
                acc += v;
            }
        }
        ushort4 o;
        o.x = f2bf(acc.x); o.y = f2bf(acc.y); o.z = f2bf(acc.z); o.w = f2bf(acc.w);
        *(ushort4*)&mid[((size_t)(b * NQ_ + q0 + ql)) * 256 + sub * 4] = o;
    }
}

// ---------------------------------------------------------------------------
extern "C" void kernel_launch(void* const* d_in, const int* in_sizes, int n_in,
                              void* d_out, int out_size, void* d_ws, size_t ws_size,
                              hipStream_t stream) {
    const float* query = (const float*)d_in[0];
    const float* refp  = (const float*)d_in[1];
    const float* value = (const float*)d_in[2];
    const float* Wt = (const float*)d_in[5];
    const float* bt = (const float*)d_in[6];
    const float* Wf = (const float*)d_in[7];
    const float* bf = (const float*)d_in[8];
    const float* Wl = (const float*)d_in[9];
    const float* bl = (const float*)d_in[10];
    const float* Wp = (const float*)d_in[11];
    const float* bp = (const float*)d_in[12];
    const float* Wv = (const float*)d_in[13];
    const float* bv = (const float*)d_in[14];
    const float* Wo = (const float*)d_in[15];
    const float* bo = (const float*)d_in[16];

    // ws layout (aliasing: qbf dies before params written; logits dies before mid)
    char* wsb = (char*)d_ws;
    ushort* vperm  = (ushort*)wsb;                       // 12,156,928 B (bf16 slabs)
    float*  params = (float*)(wsb + 12156928);           // 33,554,432 B
    ushort* qbf    = (ushort*)(wsb + 12156928);          // 16,777,216 B (aliases params)
    float*  logits = (float*)(wsb + 45711360);           // 37,748,736 B
    ushort* midb   = (ushort*)(wsb + 45711360);          // 16,777,216 B (aliases logits)
    ushort* Wvt    = (ushort*)(wsb + 83460096);          // 131,072 B
    ushort* Wot    = (ushort*)(wsb + 83591168);          // 131,072 B
    ushort* Wqt    = (ushort*)(wsb + 83722240);          // 147,456 B

    // converts + zeroing
    k_cvtw<<<256, 256, 0, stream>>>(Wv, Wvt);
    k_cvtw<<<256, 256, 0, stream>>>(Wo, Wot);
    k_cvtwq<<<288, 256, 0, stream>>>(Wt, Wf, Wl, Wp, Wqt);
    k_cvta<<<4096, 256, 0, stream>>>(query, qbf);        // 32768*256 / 2048
    k_zero<<<2968, 256, 0, stream>>>((uint4*)vperm);     // 12,156,928 / 4096

    // value projection (MFMA, fp32 A), padded bf16 slab store
    k_gemm<128, 1, 1><<<dim3(170, 2), 256, 0, stream>>>(value, Wvt, bv, vperm);
    // query projections (MFMA, bf16 A) -> raw logits
    k_gemm<96, 2, 0><<<dim3(256, 3), 256, 0, stream>>>(qbf, Wqt, nullptr, logits);
    // epilogue -> params (overwrites qbf region; qbf dead)
    k_epi<<<4096, 256, 0, stream>>>(logits, refp, bt, bf, bl, bp, params);
    // bilinear sampling + attention -> bf16 mid (overwrites logits; dead)
    k_sample<<<dim3(NQ_ / 8, B_), 256, 0, stream>>>(vperm, params, midb);
    // output projection (MFMA, bf16 A)
    k_gemm<128, 0, 0><<<dim3(256, 2), 256, 0, stream>>>(midb, Wot, bo, (float*)d_out);
}